// Round 3
// baseline (31198.465 us; speedup 1.0000x reference)
//
#include <hip/hip_runtime.h>
#include <hip/hip_cooperative_groups.h>
#include <hip/hip_bf16.h>
#include <math.h>

namespace cg = cooperative_groups;

// V=32000 E=512 H=1024 A=1024 L=2 B=16 T=64 S=64
typedef __bf16 bf16x8 __attribute__((ext_vector_type(8)));
typedef __bf16 bf16x4 __attribute__((ext_vector_type(4)));
typedef float  f32x4  __attribute__((ext_vector_type(4)));

__device__ __forceinline__ float sigm(float x){ return 1.0f/(1.0f+expf(-x)); }
__device__ __forceinline__ f32x4 ld4(const float* p){ return *(const f32x4*)p; }

// ---------- transpose fp32: in[R][C] -> out[C][R] ----------
__global__ __launch_bounds__(256) void k_transpose(const float* __restrict__ in,
                                                   float* __restrict__ out, int R, int C){
  __shared__ float tile[32][33];
  int c0 = blockIdx.x*32, r0 = blockIdx.y*32;
  int tx = threadIdx.x & 31, ty = threadIdx.x >> 5;
  for(int i=ty;i<32;i+=8) tile[i][tx] = in[(size_t)(r0+i)*C + c0+tx];
  __syncthreads();
  for(int i=ty;i<32;i+=8) out[(size_t)(c0+i)*R + r0+tx] = tile[tx][i];
}

// ---------- transpose + bf16 hi/lo split: in[R][C] fp32 -> out_h/l[C][R] ----------
__global__ __launch_bounds__(256) void k_transpose_split(const float* __restrict__ in,
                                                         __bf16* __restrict__ oh,
                                                         __bf16* __restrict__ ol, int R, int C){
  __shared__ float tile[32][33];
  int c0 = blockIdx.x*32, r0 = blockIdx.y*32;
  int tx = threadIdx.x & 31, ty = threadIdx.x >> 5;
  for(int i=ty;i<32;i+=8) tile[i][tx] = in[(size_t)(r0+i)*C + c0+tx];
  __syncthreads();
  for(int i=ty;i<32;i+=8){
    float x = tile[tx][i];
    __bf16 h = (__bf16)x;
    oh[(size_t)(c0+i)*R + r0+tx] = h;
    ol[(size_t)(c0+i)*R + r0+tx] = (__bf16)(x - (float)h);
  }
}

// ---------- fp32 -> bf16 hi/lo split ----------
__global__ __launch_bounds__(256) void k_cvt_split(const float* __restrict__ in,
                                                   __bf16* __restrict__ oh,
                                                   __bf16* __restrict__ ol, int n){
  int i = blockIdx.x*256 + threadIdx.x;
  if(i>=n) return;
  float x = in[i];
  __bf16 h = (__bf16)x;
  oh[i] = h;
  ol[i] = (__bf16)(x - (float)h);
}

// ---------- gather + split: et[(t*16+b)][e] = emb[tgt[b][t]][e] ----------
__global__ __launch_bounds__(256) void k_gather_split(const int* __restrict__ tgt,
                                                      const float* __restrict__ emb,
                                                      __bf16* __restrict__ oh,
                                                      __bf16* __restrict__ ol){
  int m = blockIdx.x;            // m = t*16+b
  int t = m >> 4, b = m & 15;
  int row = tgt[b*64 + t];
  const float* src = emb + (size_t)row*512;
  for(int e=threadIdx.x;e<512;e+=256){
    float x = src[e];
    __bf16 h = (__bf16)x;
    oh[(size_t)m*512 + e] = h;
    ol[(size_t)m*512 + e] = (__bf16)(x - (float)h);
  }
}

// ---------- setup GEMM: C[m][n] = sum_k A[m][k]*B[n][k] + bias[n]
// A,B pre-split bf16 hi/lo; fp32-accurate via (ah*bh + ah*bl + al*bh).
// BM=128 BN=64 BK=32, 256 thr (4 waves, wave tile 64x32). grid (M/128, N/64).
__global__ __launch_bounds__(256) void k_gemm_split(
    const __bf16* __restrict__ Ah, const __bf16* __restrict__ Al, int lda,
    const __bf16* __restrict__ Bh, const __bf16* __restrict__ Bl, int ldb,
    const float* __restrict__ bias, float* __restrict__ C, int N, int K)
{
  __shared__ __align__(16) __bf16 Ash[128][40];
  __shared__ __align__(16) __bf16 Asl[128][40];
  __shared__ __align__(16) __bf16 Bsh[64][40];
  __shared__ __align__(16) __bf16 Bsl[64][40];
  int tid = threadIdx.x;
  int m0 = blockIdx.x*128, n0 = blockIdx.y*64;
  int lane = tid & 63, wave = tid >> 6;
  int wr = wave >> 1, wc = wave & 1;
  int qq = lane >> 4, rr = lane & 15;
  f32x4 acc[4][2] = {};
  int ar = tid >> 1, ak = (tid & 1) * 16;
  int br = tid >> 2, bk = (tid & 3) * 8;
  for(int k0=0;k0<K;k0+=32){
    bf16x8 a0 = *(const bf16x8*)(Ah + (size_t)(m0+ar)*lda + k0 + ak);
    bf16x8 a1 = *(const bf16x8*)(Ah + (size_t)(m0+ar)*lda + k0 + ak + 8);
    bf16x8 a2 = *(const bf16x8*)(Al + (size_t)(m0+ar)*lda + k0 + ak);
    bf16x8 a3 = *(const bf16x8*)(Al + (size_t)(m0+ar)*lda + k0 + ak + 8);
    bf16x8 b0 = *(const bf16x8*)(Bh + (size_t)(n0+br)*ldb + k0 + bk);
    bf16x8 b1 = *(const bf16x8*)(Bl + (size_t)(n0+br)*ldb + k0 + bk);
    __syncthreads();
    *(bf16x8*)&Ash[ar][ak]   = a0; *(bf16x8*)&Ash[ar][ak+8] = a1;
    *(bf16x8*)&Asl[ar][ak]   = a2; *(bf16x8*)&Asl[ar][ak+8] = a3;
    *(bf16x8*)&Bsh[br][bk]   = b0; *(bf16x8*)&Bsl[br][bk]   = b1;
    __syncthreads();
    bf16x8 afh[4], afl[4], bfh[2], bfl[2];
    #pragma unroll
    for(int mi=0;mi<4;++mi){
      afh[mi] = *(const bf16x8*)&Ash[wr*64 + mi*16 + rr][qq*8];
      afl[mi] = *(const bf16x8*)&Asl[wr*64 + mi*16 + rr][qq*8];
    }
    #pragma unroll
    for(int ni=0;ni<2;++ni){
      bfh[ni] = *(const bf16x8*)&Bsh[wc*32 + ni*16 + rr][qq*8];
      bfl[ni] = *(const bf16x8*)&Bsl[wc*32 + ni*16 + rr][qq*8];
    }
    #pragma unroll
    for(int mi=0;mi<4;++mi)
      #pragma unroll
      for(int ni=0;ni<2;++ni){
        acc[mi][ni] = __builtin_amdgcn_mfma_f32_16x16x32_bf16(afh[mi], bfh[ni], acc[mi][ni], 0,0,0);
        acc[mi][ni] = __builtin_amdgcn_mfma_f32_16x16x32_bf16(afh[mi], bfl[ni], acc[mi][ni], 0,0,0);
        acc[mi][ni] = __builtin_amdgcn_mfma_f32_16x16x32_bf16(afl[mi], bfh[ni], acc[mi][ni], 0,0,0);
      }
  }
  #pragma unroll
  for(int mi=0;mi<4;++mi)
    #pragma unroll
    for(int ni=0;ni<2;++ni)
      #pragma unroll
      for(int i=0;i<4;++i){
        int m = m0 + wr*64 + mi*16 + qq*4 + i;
        int n = n0 + wc*32 + ni*16 + rr;
        C[(size_t)m*N + n] = acc[mi][ni][i] + (bias? bias[n] : 0.f);
      }
}

// ---------- GEMV core for the persistent kernel ----------
// 512 thr: jl=tid&3 (f32x4 of j), b=(tid>>2)&15, kq=tid>>6 (8 K-slices of 128).
// Returns, for tid<64 (b2=tid>>2, j2=tid&3): out[b2][j0 + j2*4 .. +3].
__device__ __forceinline__ f32x4 gemv_core(const float* __restrict__ h,
                                           const float* __restrict__ W, int ldw,
                                           int j0, f32x4* red){
  int tid = threadIdx.x;
  int jl = tid & 3, b = (tid>>2)&15, kq = tid>>6;
  __syncthreads();                       // guard smem reuse across calls/phases
  const float* hp = h + b*1024 + kq*128;
  const float* wp = W + (size_t)(kq*128)*ldw + j0 + jl*4;
  f32x4 acc = {0.f,0.f,0.f,0.f};
  for(int k0=0;k0<128;k0+=16){
    f32x4 h4[4];
    #pragma unroll
    for(int i=0;i<4;++i) h4[i] = ld4(hp + k0 + i*4);
    f32x4 w[16];
    #pragma unroll
    for(int kk=0;kk<16;++kk) w[kk] = ld4(wp + (size_t)(k0+kk)*ldw);
    #pragma unroll
    for(int kk=0;kk<16;++kk) acc += h4[kk>>2][kk&3] * w[kk];
  }
  red[(kq*16 + b)*4 + jl] = acc;
  __syncthreads();
  f32x4 s = {0.f,0.f,0.f,0.f};
  if(tid < 64){
    int b2 = tid>>2, j2 = tid&3;
    #pragma unroll
    for(int k=0;k<8;++k) s += red[(k*16 + b2)*4 + j2];
  }
  return s;
}

struct RecParams {
  const float *hidden, *Whh0T, *Whh1T, *Wih1T, *Wq, *v_att, *kp, *EW, *GX0x;
  const float *b_hh0, *b_ih1, *b_hh1;
  float *gh0, *gh1, *q, *escore, *h0A, *h0B, *h1A, *h1B;
  __bf16 *Hb;
};

// ---------- persistent cooperative recurrence: 256 blocks x 512 threads ----------
__global__ __launch_bounds__(512) void k_rec(RecParams P){
  cg::grid_group grid = cg::this_grid();
  __shared__ f32x4 smem[1536];    // 24 KB
  int blk = blockIdx.x, tid = threadIdx.x;

  // boot: gh0(0) = h0(0) @ Whh0T  (192 blocks)
  if(blk >= 64){
    f32x4 s = gemv_core(P.hidden, P.Whh0T, 3072, (blk-64)*16, smem);
    if(tid < 64) *(f32x4*)(P.gh0 + (size_t)(tid>>2)*3072 + (blk-64)*16 + (tid&3)*4) = s;
  }
  grid.sync();

  for(int t=0;t<64;++t){
    const float* h0i = (t==0)? P.hidden           : ((t&1)? P.h0A : P.h0B);
    float*       h0o = (t&1)? P.h0B : P.h0A;
    const float* h1i = (t==0)? P.hidden + 16*1024 : ((t&1)? P.h1A : P.h1B);
    float*       h1o = (t&1)? P.h1B : P.h1A;

    // P1: gh1 = h1@Whh1T (192 blk) ; q = h1@Wq (64 blk)
    if(blk < 192){
      f32x4 s = gemv_core(h1i, P.Whh1T, 3072, blk*16, smem);
      if(tid < 64) *(f32x4*)(P.gh1 + (size_t)(tid>>2)*3072 + blk*16 + (tid&3)*4) = s;
    } else {
      f32x4 s = gemv_core(h1i, P.Wq, 1024, (blk-192)*16, smem);
      if(tid < 64) *(f32x4*)(P.q + (size_t)(tid>>2)*1024 + (blk-192)*16 + (tid&3)*4) = s;
    }
    grid.sync();

    // P2: escore[idx] = exp(v . tanh(q + kp)); 4 (b,s) pairs per block
    {
      int pair = tid >> 7;                // 0..3
      int idx  = blk*4 + pair;            // b*64+s
      int b = idx >> 6;
      int l = tid & 127;
      const float* qp  = P.q  + b*1024 + l*8;
      const float* kpp = P.kp + (size_t)idx*1024 + l*8;
      const float* vp  = P.v_att + l*8;
      f32x4 q0=ld4(qp), q1=ld4(qp+4), k0=ld4(kpp), k1=ld4(kpp+4), v0=ld4(vp), v1=ld4(vp+4);
      float acc = 0.f;
      #pragma unroll
      for(int e=0;e<4;++e) acc += v0[e]*tanhf(q0[e]+k0[e]) + v1[e]*tanhf(q1[e]+k1[e]);
      #pragma unroll
      for(int o=1;o<64;o<<=1) acc += __shfl_xor(acc, o);
      float* sf = (float*)smem;
      __syncthreads();
      if((tid&63)==0) sf[tid>>6] = acc;
      __syncthreads();
      if((tid&127)==0) P.escore[idx] = expf(sf[tid>>6] + sf[(tid>>6)+1]);
    }
    grid.sync();

    // P3: h0n — j-tile 4 per block; thread (b=tid&15, sq=tid>>4) covers 2 s.
    {
      int j0 = blk*4;
      int b = tid & 15, sq = tid >> 4;
      int s0 = sq*2;
      const float* ew = P.EW + (size_t)(b*64+s0)*3072 + j0;
      float e0 = P.escore[b*64+s0], e1 = P.escore[b*64+s0+1];
      f32x4 ar = e0*ld4(ew)      + e1*ld4(ew+3072);
      f32x4 az = e0*ld4(ew+1024) + e1*ld4(ew+4096);
      f32x4 an = e0*ld4(ew+2048) + e1*ld4(ew+5120);
      __syncthreads();
      smem[(sq*16+b)*3+0] = ar;
      smem[(sq*16+b)*3+1] = az;
      smem[(sq*16+b)*3+2] = an;
      __syncthreads();
      if(tid < 64){
        int b2 = tid>>2, jq = tid&3; int j = j0 + jq;
        float xr=0.f, xz=0.f, xn=0.f;
        #pragma unroll 8
        for(int k2=0;k2<32;++k2){
          xr += smem[(k2*16+b2)*3+0][jq];
          xz += smem[(k2*16+b2)*3+1][jq];
          xn += smem[(k2*16+b2)*3+2][jq];
        }
        float den = 0.f;
        const float* ep = P.escore + b2*64;
        #pragma unroll 8
        for(int s2=0;s2<64;++s2) den += ep[s2];
        float inv = 1.0f/den;
        const float* gx = P.GX0x + ((size_t)t*16 + b2)*3072 + j;
        const float* g0 = P.gh0 + (size_t)b2*3072 + j;
        float r = sigm(xr*inv + gx[0]    + g0[0]    + P.b_hh0[j]);
        float z = sigm(xz*inv + gx[1024] + g0[1024] + P.b_hh0[1024+j]);
        float n = tanhf(xn*inv + gx[2048] + r*(g0[2048] + P.b_hh0[2048+j]));
        float hold = h0i[b2*1024 + j];
        h0o[b2*1024 + j] = (1.f-z)*n + z*hold;
      }
    }
    grid.sync();

    // P4: blocks 0..63: g1x (3 gates) + GRU1 -> h1n + Hb ; blocks 64..255: gh0(t+1)
    if(blk < 64){
      int j0 = blk*16;
      f32x4 gr = gemv_core(h0o, P.Wih1T, 3072, j0,        smem);
      f32x4 gz = gemv_core(h0o, P.Wih1T, 3072, j0 + 1024, smem);
      f32x4 gn = gemv_core(h0o, P.Wih1T, 3072, j0 + 2048, smem);
      if(tid < 64){
        int b2 = tid>>2, jq = tid&3; int j = j0 + jq*4;
        f32x4 xr = gr + ld4(P.b_ih1 + j);
        f32x4 xz = gz + ld4(P.b_ih1 + 1024 + j);
        f32x4 xn = gn + ld4(P.b_ih1 + 2048 + j);
        const float* g1 = P.gh1 + (size_t)b2*3072 + j;
        f32x4 hr = ld4(g1)        + ld4(P.b_hh1 + j);
        f32x4 hz = ld4(g1 + 1024) + ld4(P.b_hh1 + 1024 + j);
        f32x4 hn = ld4(g1 + 2048) + ld4(P.b_hh1 + 2048 + j);
        f32x4 hold = ld4(h1i + b2*1024 + j);
        f32x4 hnew; bf16x4 hb;
        #pragma unroll
        for(int e=0;e<4;++e){
          float r = sigm(xr[e] + hr[e]);
          float z = sigm(xz[e] + hz[e]);
          float n = tanhf(xn[e] + r*hn[e]);
          hnew[e] = (1.f-z)*n + z*hold[e];
          hb[e] = (__bf16)hnew[e];
        }
        *(f32x4*)(h1o + b2*1024 + j) = hnew;
        *(bf16x4*)(P.Hb + ((size_t)t*16 + b2)*1024 + j) = hb;
      }
    } else {
      f32x4 s = gemv_core(h0o, P.Whh0T, 3072, (blk-64)*16, smem);
      if(tid < 64) *(f32x4*)(P.gh0 + (size_t)(tid>>2)*3072 + (blk-64)*16 + (tid&3)*4) = s;
    }
    grid.sync();
  }
}

// ---------- logits: BM=256, BN=128, 512 thr (8 waves 4x2), XCD-chunked swizzle ----------
__global__ __launch_bounds__(512) void k_logits(
    const __bf16* __restrict__ Hb, const float* __restrict__ Wout,
    const float* __restrict__ b_out, float* __restrict__ out)
{
  int c = blockIdx.x & 7, j = blockIdx.x >> 3;
  int x = j & 3, y = (j >> 2)*8 + c;
  if(y >= 250) return;
  int tm0 = x*256, tn0 = y*128;
  __shared__ __align__(16) __bf16 As[256][40];
  __shared__ __align__(16) __bf16 Bs[128][40];
  int tid = threadIdx.x;
  int lane = tid & 63, wave = tid >> 6;
  int wr = wave >> 1, wc = wave & 1;     // wave tile 64(m) x 64(n)
  int qq = lane >> 4, rr = lane & 15;
  f32x4 acc[4][4] = {};
  int ar = tid >> 2, ak = (tid & 3) * 8;
  for(int k0=0;k0<1024;k0+=32){
    bf16x8 a0v = *(const bf16x8*)(Hb + (size_t)(tm0+ar)*1024     + k0 + ak);
    bf16x8 a1v = *(const bf16x8*)(Hb + (size_t)(tm0+ar+128)*1024 + k0 + ak);
    const float* bp = Wout + (size_t)(tn0+ar)*1024 + k0 + ak;
    f32x4 f0 = ld4(bp), f1 = ld4(bp+4);
    __syncthreads();
    *(bf16x8*)&As[ar][ak]     = a0v;
    *(bf16x8*)&As[ar+128][ak] = a1v;
    bf16x8 bv;
    #pragma unroll
    for(int i=0;i<4;++i){ bv[i]=(__bf16)f0[i]; bv[4+i]=(__bf16)f1[i]; }
    *(bf16x8*)&Bs[ar][ak] = bv;
    __syncthreads();
    bf16x8 af[4], bfr[4];
    #pragma unroll
    for(int mi=0;mi<4;++mi) af[mi]  = *(const bf16x8*)&As[wr*64 + mi*16 + rr][qq*8];
    #pragma unroll
    for(int ni=0;ni<4;++ni) bfr[ni] = *(const bf16x8*)&Bs[wc*64 + ni*16 + rr][qq*8];
    #pragma unroll
    for(int mi=0;mi<4;++mi)
      #pragma unroll
      for(int ni=0;ni<4;++ni)
        acc[mi][ni] = __builtin_amdgcn_mfma_f32_16x16x32_bf16(af[mi], bfr[ni], acc[mi][ni], 0,0,0);
  }
  #pragma unroll
  for(int mi=0;mi<4;++mi)
    #pragma unroll
    for(int ni=0;ni<4;++ni)
      #pragma unroll
      for(int i=0;i<4;++i){
        int m = tm0 + wr*64 + mi*16 + qq*4 + i;
        int v = tn0 + wc*64 + ni*16 + rr;
        int bb = m & 15, tt = m >> 4;
        out[((size_t)bb*64 + tt)*32000 + v] = acc[mi][ni][i] + b_out[v];
      }
}

extern "C" void kernel_launch(void* const* d_in, const int* in_sizes, int n_in,
                              void* d_out, int out_size, void* d_ws, size_t ws_size,
                              hipStream_t stream){
  const int*   tgt    = (const int*)d_in[0];
  const float* hidden = (const float*)d_in[1];
  const float* enc    = (const float*)d_in[2];
  const float* emb    = (const float*)d_in[3];
  const float* Wq     = (const float*)d_in[4];
  const float* Wk     = (const float*)d_in[5];
  const float* v_att  = (const float*)d_in[6];
  const float* W_ih0  = (const float*)d_in[7];
  const float* W_hh0  = (const float*)d_in[8];
  const float* b_ih0  = (const float*)d_in[9];
  const float* b_hh0  = (const float*)d_in[10];
  const float* b_ih1  = (const float*)d_in[11];  // W_ih1 actually index 11
  (void)b_ih1;
  const float* W_ih1  = (const float*)d_in[11];
  const float* W_hh1  = (const float*)d_in[12];
  const float* b_ih1r = (const float*)d_in[13];
  const float* b_hh1  = (const float*)d_in[14];
  const float* W_out  = (const float*)d_in[15];
  const float* b_out  = (const float*)d_in[16];
  float* out = (float*)d_out;

  float* ws = (float*)d_ws;
  size_t off = 0;
  auto alloc = [&](size_t n){ float* p = ws + off; off += n; return p; };
  float* kp     = alloc((size_t)1024*1024);
  float* GX0x   = alloc((size_t)1024*3072);
  float* EW     = alloc((size_t)1024*3072);
  float* Wih1T  = alloc((size_t)1024*3072);
  float* REGION = alloc((size_t)7340032);     // union: setup splits / Whh0T+Whh1T
  float* gh0    = alloc((size_t)16*3072);
  float* gh1    = alloc((size_t)16*3072);
  float* q      = alloc((size_t)16*1024);
  float* escore = alloc((size_t)16*64);
  float* h0A    = alloc((size_t)16*1024);
  float* h0B    = alloc((size_t)16*1024);
  float* h1A    = alloc((size_t)16*1024);
  float* h1B    = alloc((size_t)16*1024);
  float* Hb_f   = alloc((size_t)512*1024);
  __bf16* Hb    = (__bf16*)Hb_f;
  (void)ws_size; (void)in_sizes; (void)n_in; (void)out_size;

  // setup-phase aliases inside REGION (word offsets)
  __bf16* enc_h  = (__bf16*)(REGION + 0);
  __bf16* enc_l  = (__bf16*)(REGION + 524288);
  __bf16* et_h   = (__bf16*)(REGION + 1048576);
  __bf16* et_l   = (__bf16*)(REGION + 1310720);
  __bf16* wkt_h  = (__bf16*)(REGION + 1572864);
  __bf16* wkt_l  = (__bf16*)(REGION + 2097152);
  __bf16* wih0_h = (__bf16*)(REGION + 2621440);
  __bf16* wih0_l = (__bf16*)(REGION + 4980736);
  // recurrence-phase aliases (written AFTER the setup GEMMs complete)
  float* Whh0T = REGION + 0;
  float* Whh1T = REGION + 3145728;

  // ---- setup: splits + MFMA GEMMs (fp32-accurate via hi/lo) ----
  k_cvt_split<<<4096,256,0,stream>>>(enc, enc_h, enc_l, 1024*1024);
  k_gather_split<<<1024,256,0,stream>>>(tgt, emb, et_h, et_l);
  k_transpose_split<<<dim3(32,32),256,0,stream>>>(Wk, wkt_h, wkt_l, 1024, 1024);
  k_cvt_split<<<18432,256,0,stream>>>(W_ih0, wih0_h, wih0_l, 3072*1536);
  // kp = enc @ Wk
  k_gemm_split<<<dim3(8,16),256,0,stream>>>(enc_h, enc_l, 1024, wkt_h, wkt_l, 1024,
                                            nullptr, kp, 1024, 1024);
  // GX0x = emb_tok @ Wx^T + b_ih0   (Wx = W_ih0[:, :512])
  k_gemm_split<<<dim3(8,48),256,0,stream>>>(et_h, et_l, 512, wih0_h, wih0_l, 1536,
                                            b_ih0, GX0x, 3072, 512);
  // EW = enc @ Wc^T                 (Wc = W_ih0[:, 512:1536])
  k_gemm_split<<<dim3(8,48),256,0,stream>>>(enc_h, enc_l, 1024, wih0_h+512, wih0_l+512, 1536,
                                            nullptr, EW, 3072, 1024);
  // transposes for the recurrence (overwrite the dead split region)
  k_transpose<<<dim3(32,96),256,0,stream>>>(W_hh0, Whh0T, 3072, 1024);
  k_transpose<<<dim3(32,96),256,0,stream>>>(W_hh1, Whh1T, 3072, 1024);
  k_transpose<<<dim3(32,96),256,0,stream>>>(W_ih1, Wih1T, 3072, 1024);

  // ---- persistent cooperative recurrence ----
  RecParams P;
  P.hidden = hidden; P.Whh0T = Whh0T; P.Whh1T = Whh1T; P.Wih1T = Wih1T;
  P.Wq = Wq; P.v_att = v_att; P.kp = kp; P.EW = EW; P.GX0x = GX0x;
  P.b_hh0 = b_hh0; P.b_ih1 = b_ih1r; P.b_hh1 = b_hh1;
  P.gh0 = gh0; P.gh1 = gh1; P.q = q; P.escore = escore;
  P.h0A = h0A; P.h0B = h0B; P.h1A = h1A; P.h1B = h1B; P.Hb = Hb;
  void* args[] = { &P };
  hipLaunchCooperativeKernel((const void*)k_rec, dim3(256), dim3(512), args, 0, stream);

  // ---- deferred logits ----
  k_logits<<<1024,512,0,stream>>>(Hb, W_out, b_out, out);
}

// Round 4
// 2092.888 us; speedup vs baseline: 14.9069x; 14.9069x over previous
//
#include <hip/hip_runtime.h>
#include <hip/hip_bf16.h>
#include <math.h>

// V=32000 E=512 H=1024 A=1024 L=2 B=16 T=64 S=64
typedef __bf16 bf16x8 __attribute__((ext_vector_type(8)));
typedef float  f32x4  __attribute__((ext_vector_type(4)));

__device__ __forceinline__ float sigm(float x){ return 1.0f/(1.0f+expf(-x)); }
__device__ __forceinline__ f32x4 ld4(const float* p){ return *(const f32x4*)p; }
__device__ __forceinline__ void split2(float x, __bf16* h, __bf16* l){
  __bf16 hh = (__bf16)x; *h = hh; *l = (__bf16)(x - (float)hh);
}

// ---------- transpose fp32 ----------
__global__ __launch_bounds__(256) void k_transpose(const float* __restrict__ in,
                                                   float* __restrict__ out, int R, int C){
  __shared__ float tile[32][33];
  int c0 = blockIdx.x*32, r0 = blockIdx.y*32;
  int tx = threadIdx.x & 31, ty = threadIdx.x >> 5;
  for(int i=ty;i<32;i+=8) tile[i][tx] = in[(size_t)(r0+i)*C + c0+tx];
  __syncthreads();
  for(int i=ty;i<32;i+=8) out[(size_t)(c0+i)*R + r0+tx] = tile[tx][i];
}

// ---------- gather fp32 ----------
__global__ __launch_bounds__(256) void k_gather(const int* __restrict__ tgt,
                                                const float* __restrict__ emb,
                                                float* __restrict__ emb_tok){
  int m = blockIdx.x;            // m = t*16+b
  int t = m >> 4, b = m & 15;
  int row = tgt[b*64 + t];
  const float* src = emb + (size_t)row*512;
  float* dst = emb_tok + (size_t)m*512;
  for(int e=threadIdx.x;e<512;e+=256) dst[e] = src[e];
}

// ---------- setup GEMM: C[m][n] = sum_k A[m][k]*Bt[n][k] + bias[n]
// fp32 in, split to bf16 hi/lo at LDS staging, 3-term MFMA (fp32-accurate).
__global__ __launch_bounds__(256) void k_gemm_s(
    const float* __restrict__ A, int lda,
    const float* __restrict__ Bt, int ldb,
    const float* __restrict__ bias,
    float* __restrict__ C, int N, int K)
{
  __shared__ __align__(16) __bf16 Ash[128][40];
  __shared__ __align__(16) __bf16 Asl[128][40];
  __shared__ __align__(16) __bf16 Bsh[64][40];
  __shared__ __align__(16) __bf16 Bsl[64][40];
  int tid = threadIdx.x;
  int m0 = blockIdx.x*128, n0 = blockIdx.y*64;
  int lane = tid & 63, wave = tid >> 6;
  int wr = wave >> 1, wc = wave & 1;
  int qq = lane >> 4, rr = lane & 15;
  f32x4 acc[4][2] = {};
  int ar = tid >> 1, ak = (tid & 1)*16;
  int br = tid >> 2, bk = (tid & 3)*8;
  for(int k0=0;k0<K;k0+=32){
    const float* ap = A + (size_t)(m0+ar)*lda + k0 + ak;
    f32x4 a0 = ld4(ap), a1 = ld4(ap+4), a2 = ld4(ap+8), a3 = ld4(ap+12);
    const float* bp = Bt + (size_t)(n0+br)*ldb + k0 + bk;
    f32x4 b0 = ld4(bp), b1 = ld4(bp+4);
    __syncthreads();
    #pragma unroll
    for(int e=0;e<4;++e){
      split2(a0[e], &Ash[ar][ak+e],    &Asl[ar][ak+e]);
      split2(a1[e], &Ash[ar][ak+4+e],  &Asl[ar][ak+4+e]);
      split2(a2[e], &Ash[ar][ak+8+e],  &Asl[ar][ak+8+e]);
      split2(a3[e], &Ash[ar][ak+12+e], &Asl[ar][ak+12+e]);
      split2(b0[e], &Bsh[br][bk+e],    &Bsl[br][bk+e]);
      split2(b1[e], &Bsh[br][bk+4+e],  &Bsl[br][bk+4+e]);
    }
    __syncthreads();
    bf16x8 afh[4], afl[4], bfh[2], bfl[2];
    #pragma unroll
    for(int mi=0;mi<4;++mi){
      afh[mi] = *(const bf16x8*)&Ash[wr*64 + mi*16 + rr][qq*8];
      afl[mi] = *(const bf16x8*)&Asl[wr*64 + mi*16 + rr][qq*8];
    }
    #pragma unroll
    for(int ni=0;ni<2;++ni){
      bfh[ni] = *(const bf16x8*)&Bsh[wc*32 + ni*16 + rr][qq*8];
      bfl[ni] = *(const bf16x8*)&Bsl[wc*32 + ni*16 + rr][qq*8];
    }
    #pragma unroll
    for(int mi=0;mi<4;++mi)
      #pragma unroll
      for(int ni=0;ni<2;++ni){
        acc[mi][ni] = __builtin_amdgcn_mfma_f32_16x16x32_bf16(afh[mi], bfh[ni], acc[mi][ni], 0,0,0);
        acc[mi][ni] = __builtin_amdgcn_mfma_f32_16x16x32_bf16(afl[mi], bfh[ni], acc[mi][ni], 0,0,0);
        acc[mi][ni] = __builtin_amdgcn_mfma_f32_16x16x32_bf16(afh[mi], bfl[ni], acc[mi][ni], 0,0,0);
      }
  }
  #pragma unroll
  for(int mi=0;mi<4;++mi)
    #pragma unroll
    for(int ni=0;ni<2;++ni)
      #pragma unroll
      for(int i=0;i<4;++i){
        int m = m0 + wr*64 + mi*16 + qq*4 + i;
        int n = n0 + wc*32 + ni*16 + rr;
        C[(size_t)m*N + n] = acc[mi][ni][i] + (bias? bias[n] : 0.f);
      }
}

// ---------- pack W[J rows][1024 k] fp32 -> MFMA B-frag panels, bf16 hi/lo ----------
// Wp[(jt*32+kt)*1024 + l*8 + e] (hi), +512 (lo), where value = W[jt*16+(l&15)][kt*32+(l>>4)*8+e]
__global__ __launch_bounds__(256) void k_pack_w(const float* __restrict__ W,
                                                __bf16* __restrict__ Wp){
  int jt = blockIdx.x, tid = threadIdx.x;
  #pragma unroll
  for(int it=0; it<8; ++it){
    int pos = it*256 + tid;           // 0..2047
    int kt = pos>>6, l = pos&63;
    const float* src = W + (size_t)(jt*16 + (l&15))*1024 + kt*32 + (l>>4)*8;
    f32x4 s0 = ld4(src), s1 = ld4(src+4);
    bf16x8 vh, vl;
    #pragma unroll
    for(int e=0;e<4;++e){
      __bf16 h, lo;
      split2(s0[e], &h, &lo); vh[e]   = h; vl[e]   = lo;
      split2(s1[e], &h, &lo); vh[4+e] = h; vl[4+e] = lo;
    }
    __bf16* dst = Wp + ((size_t)(jt*32 + kt))*1024 + l*8;
    *(bf16x8*)dst       = vh;
    *(bf16x8*)(dst+512) = vl;
  }
}

// ---------- split hidden -> h0/h1 bf16 hi/lo ----------
__global__ __launch_bounds__(256) void k_split_h(const float* __restrict__ hidden,
    __bf16* __restrict__ h0h, __bf16* __restrict__ h0l,
    __bf16* __restrict__ h1h, __bf16* __restrict__ h1l){
  int i = blockIdx.x*256 + threadIdx.x;   // 0..32767
  float x = hidden[i];
  if(i < 16384) split2(x, &h0h[i], &h0l[i]);
  else { int j = i - 16384; split2(x, &h1h[j], &h1l[j]); }
}

// ---------- MFMA GEMV: out[16 b][16 j] for one j-tile, K=1024 ----------
// 256 thr = 4 waves (k-split). A = h splits (L2-hot), B = packed panel (dense 1KB loads).
__device__ __forceinline__ void mfma_gemv16(const __bf16* __restrict__ hh,
                                            const __bf16* __restrict__ hl,
                                            const __bf16* __restrict__ Wp, int jt,
                                            float* __restrict__ out, int ldo,
                                            f32x4* red){
  int tid = threadIdx.x, lane = tid & 63, w = tid >> 6;
  const __bf16* Ah = hh + (lane&15)*1024 + (lane>>4)*8;
  const __bf16* Al = hl + (lane&15)*1024 + (lane>>4)*8;
  const __bf16* Bp = Wp + ((size_t)jt*32 + w*8)*1024 + lane*8;
  f32x4 acc = {0.f,0.f,0.f,0.f};
  #pragma unroll
  for(int kk=0;kk<8;++kk){
    int k0 = (w*8 + kk)*32;
    bf16x8 ah = *(const bf16x8*)(Ah + k0);
    bf16x8 al = *(const bf16x8*)(Al + k0);
    bf16x8 bh = *(const bf16x8*)(Bp + kk*1024);
    bf16x8 bl = *(const bf16x8*)(Bp + kk*1024 + 512);
    acc = __builtin_amdgcn_mfma_f32_16x16x32_bf16(ah, bh, acc, 0,0,0);
    acc = __builtin_amdgcn_mfma_f32_16x16x32_bf16(al, bh, acc, 0,0,0);
    acc = __builtin_amdgcn_mfma_f32_16x16x32_bf16(ah, bl, acc, 0,0,0);
  }
  red[w*64 + lane] = acc;
  __syncthreads();
  if(tid < 64){
    f32x4 s = red[tid] + red[64+tid] + red[128+tid] + red[192+tid];
    int j = jt*16 + (tid & 15);
    #pragma unroll
    for(int i=0;i<4;++i) out[(size_t)((tid>>4)*4 + i)*ldo + j] = s[i];
  }
}

// ---------- boot: gh0 = h0 @ Whh0^T (raw, no bias) ----------
__global__ __launch_bounds__(256) void k_boot(const __bf16* __restrict__ hh,
                                              const __bf16* __restrict__ hl,
                                              const __bf16* __restrict__ Wp,
                                              float* __restrict__ gh0){
  __shared__ f32x4 red[256];
  mfma_gemv16(hh, hl, Wp, blockIdx.x, gh0, 3072, red);
}

// ---------- P1: gh1 = h1@Whh1^T (192 blk) ; q = h1@Wq (64 blk) ----------
__global__ __launch_bounds__(256) void k_step1(const __bf16* __restrict__ h1h,
                                               const __bf16* __restrict__ h1l,
                                               const __bf16* __restrict__ Whh1p,
                                               const __bf16* __restrict__ Wqp,
                                               float* __restrict__ gh1,
                                               float* __restrict__ q){
  __shared__ f32x4 red[256];
  int blk = blockIdx.x;
  if(blk < 192) mfma_gemv16(h1h, h1l, Whh1p, blk,     gh1, 3072, red);
  else          mfma_gemv16(h1h, h1l, Wqp,   blk-192, q,   1024, red);
}

// ---------- P2: escore[b*64+s] = exp(sum_a v[a]*tanh(q[b][a]+kp[b,s][a])) ----------
__global__ __launch_bounds__(512) void k_step2(const float* __restrict__ q,
                                               const float* __restrict__ kp,
                                               const float* __restrict__ v_att,
                                               float* __restrict__ escore){
  int pair = blockIdx.x*8 + (threadIdx.x >> 6);  // = b*64+s
  int b = pair >> 6;
  int lane = threadIdx.x & 63;
  const float* qp  = q  + b*1024 + lane*16;
  const float* kpp = kp + (size_t)pair*1024 + lane*16;
  const float* vp  = v_att + lane*16;
  float acc = 0.f;
  #pragma unroll
  for(int i=0;i<4;++i){
    f32x4 qv = ld4(qp+i*4), kv = ld4(kpp+i*4), vv = ld4(vp+i*4);
    #pragma unroll
    for(int e=0;e<4;++e) acc += vv[e]*tanhf(qv[e]+kv[e]);
  }
  #pragma unroll
  for(int o=1;o<64;o<<=1) acc += __shfl_xor(acc, o);
  if(lane==0) escore[pair] = expf(acc);   // |score| <~ 16, exp safe
}

// ---------- P3: xg = attn.EW + GX0x ; h0n = GRU0 ; write h0 splits ----------
// 256 blocks: jt = blk>>2 (16 j), bq = blk&3 (4 b). 512 thr: wave w = s-slice of 8.
__global__ __launch_bounds__(512) void k_step3(int t,
    const float* __restrict__ escore, const float* __restrict__ EW,
    const float* __restrict__ GX0x, const float* __restrict__ gh0,
    const float* __restrict__ b_hh0,
    const float* __restrict__ h0_in, float* __restrict__ h0_out,
    __bf16* __restrict__ h0h, __bf16* __restrict__ h0l)
{
  __shared__ float part[8][4][16][3];
  __shared__ float dred[4][16];
  __shared__ float sden[4];
  int blk = blockIdx.x, tid = threadIdx.x;
  int jt = blk >> 2, bq = blk & 3;
  int lane = tid & 63, w = tid >> 6;
  int bl = lane >> 4, jl = lane & 15;
  int b = bq*4 + bl;
  int col = jt*16 + jl;
  float a0=0.f, a1=0.f, a2=0.f;
  const float* ep  = escore + b*64 + w*8;
  const float* ewp = EW + ((size_t)(b*64 + w*8))*3072 + col;
  #pragma unroll
  for(int si=0; si<8; ++si){
    float e = ep[si];
    const float* r = ewp + (size_t)si*3072;
    a0 += e*r[0]; a1 += e*r[1024]; a2 += e*r[2048];
  }
  part[w][bl][jl][0]=a0; part[w][bl][jl][1]=a1; part[w][bl][jl][2]=a2;
  if(tid < 64){
    int bb = tid >> 4, si = tid & 15;
    const float* e2 = escore + (bq*4 + bb)*64;
    dred[bb][si] = e2[si] + e2[si+16] + e2[si+32] + e2[si+48];
  }
  __syncthreads();
  if(tid < 4){
    float d = 0.f;
    #pragma unroll
    for(int i=0;i<16;++i) d += dred[tid][i];
    sden[tid] = d;
  }
  __syncthreads();
  if(tid < 64){
    float xr=0.f, xz=0.f, xn=0.f;
    #pragma unroll
    for(int k=0;k<8;++k){ xr+=part[k][bl][jl][0]; xz+=part[k][bl][jl][1]; xn+=part[k][bl][jl][2]; }
    float inv = 1.0f / sden[bl];
    int j = col;
    const float* gx = GX0x + ((size_t)t*16 + b)*3072 + j;   // includes b_ih0
    const float* g0 = gh0 + (size_t)b*3072 + j;
    float r = sigm(xr*inv + gx[0]    + g0[0]    + b_hh0[j]);
    float z = sigm(xz*inv + gx[1024] + g0[1024] + b_hh0[1024+j]);
    float n = tanhf(xn*inv + gx[2048] + r*(g0[2048] + b_hh0[2048+j]));
    float hnew = (1.f-z)*n + z*h0_in[b*1024 + j];
    h0_out[b*1024 + j] = hnew;
    split2(hnew, &h0h[b*1024 + j], &h0l[b*1024 + j]);
  }
}

// ---------- P4: blk<64: g1x(3 gates)+GRU1 -> h1n, splits, Hb ; blk>=64: gh0(t+1) ----------
__global__ __launch_bounds__(256) void k_step4(int t,
    const __bf16* __restrict__ h0h, const __bf16* __restrict__ h0l,
    const __bf16* __restrict__ Wih1p, const __bf16* __restrict__ Whh0p,
    const float* __restrict__ b_ih1, const float* __restrict__ b_hh1,
    const float* __restrict__ gh1,
    const float* __restrict__ h1_in, float* __restrict__ h1_out,
    __bf16* __restrict__ h1h, __bf16* __restrict__ h1l,
    __bf16* __restrict__ Hb, float* __restrict__ gh0)
{
  __shared__ f32x4 red[256];
  __shared__ float xg[3][16][16];
  int blk = blockIdx.x, tid = threadIdx.x;
  if(blk >= 64){
    mfma_gemv16(h0h, h0l, Whh0p, blk-64, gh0, 3072, red);
    return;
  }
  int lane = tid & 63, w = tid >> 6;
  const __bf16* Ah = h0h + (lane&15)*1024 + (lane>>4)*8;
  const __bf16* Al = h0l + (lane&15)*1024 + (lane>>4)*8;
  #pragma unroll
  for(int g=0; g<3; ++g){
    int jt = g*64 + blk;
    const __bf16* Bp = Wih1p + ((size_t)jt*32 + w*8)*1024 + lane*8;
    f32x4 acc = {0.f,0.f,0.f,0.f};
    #pragma unroll
    for(int kk=0;kk<8;++kk){
      int k0 = (w*8 + kk)*32;
      bf16x8 ah = *(const bf16x8*)(Ah + k0);
      bf16x8 al = *(const bf16x8*)(Al + k0);
      bf16x8 bh = *(const bf16x8*)(Bp + kk*1024);
      bf16x8 bl = *(const bf16x8*)(Bp + kk*1024 + 512);
      acc = __builtin_amdgcn_mfma_f32_16x16x32_bf16(ah, bh, acc, 0,0,0);
      acc = __builtin_amdgcn_mfma_f32_16x16x32_bf16(al, bh, acc, 0,0,0);
      acc = __builtin_amdgcn_mfma_f32_16x16x32_bf16(ah, bl, acc, 0,0,0);
    }
    if(g) __syncthreads();
    red[w*64 + lane] = acc;
    __syncthreads();
    if(tid < 64){
      f32x4 s = red[tid] + red[64+tid] + red[128+tid] + red[192+tid];
      #pragma unroll
      for(int i=0;i<4;++i) xg[g][(tid>>4)*4 + i][tid&15] = s[i];
    }
  }
  __syncthreads();
  int b = tid >> 4, jl = tid & 15, j = blk*16 + jl;
  float xr = xg[0][b][jl] + b_ih1[j];
  float xz = xg[1][b][jl] + b_ih1[1024+j];
  float xn = xg[2][b][jl] + b_ih1[2048+j];
  const float* g1 = gh1 + (size_t)b*3072 + j;
  float r = sigm(xr + g1[0]    + b_hh1[j]);
  float z = sigm(xz + g1[1024] + b_hh1[1024+j]);
  float n = tanhf(xn + r*(g1[2048] + b_hh1[2048+j]));
  float hnew = (1.f-z)*n + z*h1_in[b*1024 + j];
  h1_out[b*1024 + j] = hnew;
  split2(hnew, &h1h[b*1024 + j], &h1l[b*1024 + j]);
  Hb[((size_t)t*16 + b)*1024 + j] = (__bf16)hnew;
}

// ---------- logits: BM=256, BN=128, 512 thr, XCD-chunked swizzle ----------
__global__ __launch_bounds__(512) void k_logits(
    const __bf16* __restrict__ Hb, const float* __restrict__ Wout,
    const float* __restrict__ b_out, float* __restrict__ out)
{
  int c = blockIdx.x & 7, j = blockIdx.x >> 3;
  int x = j & 3, y = (j >> 2)*8 + c;
  if(y >= 250) return;
  int tm0 = x*256, tn0 = y*128;
  __shared__ __align__(16) __bf16 As[256][40];
  __shared__ __align__(16) __bf16 Bs[128][40];
  int tid = threadIdx.x;
  int lane = tid & 63, wave = tid >> 6;
  int wr = wave >> 1, wc = wave & 1;
  int qq = lane >> 4, rr = lane & 15;
  f32x4 acc[4][4] = {};
  int ar = tid >> 2, ak = (tid & 3) * 8;
  for(int k0=0;k0<1024;k0+=32){
    bf16x8 a0v = *(const bf16x8*)(Hb + (size_t)(tm0+ar)*1024     + k0 + ak);
    bf16x8 a1v = *(const bf16x8*)(Hb + (size_t)(tm0+ar+128)*1024 + k0 + ak);
    const float* bp = Wout + (size_t)(tn0+ar)*1024 + k0 + ak;
    f32x4 f0 = ld4(bp), f1 = ld4(bp+4);
    __syncthreads();
    *(bf16x8*)&As[ar][ak]     = a0v;
    *(bf16x8*)&As[ar+128][ak] = a1v;
    bf16x8 bv;
    #pragma unroll
    for(int i=0;i<4;++i){ bv[i]=(__bf16)f0[i]; bv[4+i]=(__bf16)f1[i]; }
    *(bf16x8*)&Bs[ar][ak] = bv;
    __syncthreads();
    bf16x8 af[4], bfr[4];
    #pragma unroll
    for(int mi=0;mi<4;++mi) af[mi]  = *(const bf16x8*)&As[wr*64 + mi*16 + rr][qq*8];
    #pragma unroll
    for(int ni=0;ni<4;++ni) bfr[ni] = *(const bf16x8*)&Bs[wc*64 + ni*16 + rr][qq*8];
    #pragma unroll
    for(int mi=0;mi<4;++mi)
      #pragma unroll
      for(int ni=0;ni<4;++ni)
        acc[mi][ni] = __builtin_amdgcn_mfma_f32_16x16x32_bf16(af[mi], bfr[ni], acc[mi][ni], 0,0,0);
  }
  #pragma unroll
  for(int mi=0;mi<4;++mi)
    #pragma unroll
    for(int ni=0;ni<4;++ni)
      #pragma unroll
      for(int i=0;i<4;++i){
        int m = tm0 + wr*64 + mi*16 + qq*4 + i;
        int v = tn0 + wc*64 + ni*16 + rr;
        int bb = m & 15, tt = m >> 4;
        out[((size_t)bb*64 + tt)*32000 + v] = acc[mi][ni][i] + b_out[v];
      }
}

extern "C" void kernel_launch(void* const* d_in, const int* in_sizes, int n_in,
                              void* d_out, int out_size, void* d_ws, size_t ws_size,
                              hipStream_t stream){
  const int*   tgt    = (const int*)d_in[0];
  const float* hidden = (const float*)d_in[1];
  const float* enc    = (const float*)d_in[2];
  const float* emb    = (const float*)d_in[3];
  const float* Wq     = (const float*)d_in[4];
  const float* Wk     = (const float*)d_in[5];
  const float* v_att  = (const float*)d_in[6];
  const float* W_ih0  = (const float*)d_in[7];
  const float* W_hh0  = (const float*)d_in[8];
  const float* b_ih0  = (const float*)d_in[9];
  const float* b_hh0  = (const float*)d_in[10];
  const float* W_ih1  = (const float*)d_in[11];
  const float* W_hh1  = (const float*)d_in[12];
  const float* b_ih1  = (const float*)d_in[13];
  const float* b_hh1  = (const float*)d_in[14];
  const float* W_out  = (const float*)d_in[15];
  const float* b_out  = (const float*)d_in[16];
  float* out = (float*)d_out;

  float* ws = (float*)d_ws;
  size_t off = 0;
  auto alloc = [&](size_t n){ float* p = ws + off; off += n; return p; };
  float*  kp     = alloc((size_t)1024*1024);
  float*  GX0x   = alloc((size_t)1024*3072);
  float*  EW     = alloc((size_t)1024*3072);
  __bf16* Whh0p  = (__bf16*)alloc((size_t)3072*1024);  // 2x bf16 per word
  __bf16* Whh1p  = (__bf16*)alloc((size_t)3072*1024);
  __bf16* Wih1p  = (__bf16*)alloc((size_t)3072*1024);
  __bf16* Wqp    = (__bf16*)alloc((size_t)1024*1024);
  float*  gh0    = alloc((size_t)16*3072);
  float*  gh1    = alloc((size_t)16*3072);
  float*  q      = alloc((size_t)16*1024);
  float*  escore = alloc((size_t)16*64);
  float*  h0A    = alloc((size_t)16*1024);
  float*  h0B    = alloc((size_t)16*1024);
  float*  h1A    = alloc((size_t)16*1024);
  float*  h1B    = alloc((size_t)16*1024);
  __bf16* h0sh   = (__bf16*)alloc((size_t)8192);
  __bf16* h0sl   = (__bf16*)alloc((size_t)8192);
  __bf16* h1sh   = (__bf16*)alloc((size_t)8192);
  __bf16* h1sl   = (__bf16*)alloc((size_t)8192);
  __bf16* Hb     = (__bf16*)alloc((size_t)512*1024);
  float*  REGION = alloc((size_t)1572864);   // setup-only: emb_tok + WT
  float*  emb_tok = REGION;                  // 1024x512 fp32
  float*  WT      = REGION + 524288;         // 1024x1024 fp32 (WkT, then WqT)
  (void)ws_size; (void)in_sizes; (void)n_in; (void)out_size;

  // ---- setup ----
  k_gather<<<1024,256,0,stream>>>(tgt, emb, emb_tok);
  k_transpose<<<dim3(32,32),256,0,stream>>>(Wk, WT, 1024, 1024);
  // kp = enc @ Wk
  k_gemm_s<<<dim3(8,16),256,0,stream>>>(enc,1024, WT,1024, nullptr, kp, 1024, 1024);
  // GX0x = emb_tok @ Wx^T + b_ih0  (Wx = W_ih0[:, :512])
  k_gemm_s<<<dim3(8,48),256,0,stream>>>(emb_tok,512, W_ih0,1536, b_ih0, GX0x, 3072, 512);
  // EW = enc @ Wc^T                (Wc = W_ih0[:, 512:1536])
  k_gemm_s<<<dim3(8,48),256,0,stream>>>(enc,1024, W_ih0+512,1536, nullptr, EW, 3072, 1024);
  // packed MFMA panels for the recurrence
  k_transpose<<<dim3(32,32),256,0,stream>>>(Wq, WT, 1024, 1024);   // WqT[a][h]
  k_pack_w<<<64,256,0,stream>>>(WT, Wqp);
  k_pack_w<<<192,256,0,stream>>>(W_hh0, Whh0p);
  k_pack_w<<<192,256,0,stream>>>(W_hh1, Whh1p);
  k_pack_w<<<192,256,0,stream>>>(W_ih1, Wih1p);
  k_split_h<<<128,256,0,stream>>>(hidden, h0sh, h0sl, h1sh, h1sl);
  k_boot<<<192,256,0,stream>>>(h0sh, h0sl, Whh0p, gh0);

  // ---- recurrence: 4 dispatches per step ----
  for(int t=0;t<64;++t){
    const float* h0i = (t==0)? hidden            : ((t&1)? h0A : h0B);
    float*       h0o = (t&1)? h0B : h0A;
    const float* h1i = (t==0)? hidden + 16*1024  : ((t&1)? h1A : h1B);
    float*       h1o = (t&1)? h1B : h1A;
    k_step1<<<256,256,0,stream>>>(h1sh, h1sl, Whh1p, Wqp, gh1, q);
    k_step2<<<128,512,0,stream>>>(q, kp, v_att, escore);
    k_step3<<<256,512,0,stream>>>(t, escore, EW, GX0x, gh0, b_hh0, h0i, h0o, h0sh, h0sl);
    k_step4<<<256,256,0,stream>>>(t, h0sh, h0sl, Wih1p, Whh0p, b_ih1, b_hh1, gh1,
                                  h1i, h1o, h1sh, h1sl, Hb, gh0);
  }

  // ---- deferred logits ----
  k_logits<<<1024,512,0,stream>>>(Hb, W_out, b_out, out);
}